// Round 2
// baseline (9425.437 us; speedup 1.0000x reference)
//
#include <hip/hip_runtime.h>
#include <math.h>

// Problem constants
static constexpr int BB = 64, TT = 26, EE = 300, HH = 1024;
static constexpr int FEAT = 2048, SS = 49;
static constexpr int D1 = 245000, D2 = 5000;
static constexpr int MOUT = 1000;
static constexpr int VOCAB = 3000;

// MCB1 sketch layout: folded sketch with wrap-pad, no mod in gather.
static constexpr int PAD1 = 14400;                 // >= max per-thread tb span (13248) + slack
static constexpr int AEXT_STRIDE = D1 + PAD1;      // 259400 floats per batch
static constexpr int FOLD_R = 16000;               // bins per sketch_fold block
static constexpr int FOLD_NR = 16;                 // 16*16000 = 256000 >= D1
static constexpr int NITEMS = FEAT * SS;           // 100352 count-sketch items

// ---------------------------------------------------------------------------
// Generic fp32 GEMM: C[M,N] = act( A(M,K) * B(N,K)^T + bias1 + bias2 )
// ---------------------------------------------------------------------------
template <int BM, int BN, int BK, int TM, int TN, bool RELU>
__global__ void gemm_abt(const float* __restrict__ A, const float* __restrict__ B,
                         const float* __restrict__ bias1, const float* __restrict__ bias2,
                         float* __restrict__ C,
                         int M, int N, int K, int lda, int ldb, int ldc) {
    constexpr int THREADS = (BM / TM) * (BN / TN);
    __shared__ float As[BK][BM + 1];
    __shared__ float Bs[BK][BN + 1];
    const int tid = threadIdx.x;
    const int tx = tid % (BN / TN);
    const int ty = tid / (BN / TN);
    const int block_m = blockIdx.y * BM;
    const int block_n = blockIdx.x * BN;
    float acc[TM][TN];
#pragma unroll
    for (int i = 0; i < TM; i++)
#pragma unroll
        for (int j = 0; j < TN; j++) acc[i][j] = 0.f;

    for (int k0 = 0; k0 < K; k0 += BK) {
        for (int i = tid; i < BM * BK; i += THREADS) {
            int m = i / BK, kk = i % BK;
            int gm = block_m + m, gk = k0 + kk;
            As[kk][m] = (gm < M && gk < K) ? A[(size_t)gm * lda + gk] : 0.f;
        }
        for (int i = tid; i < BN * BK; i += THREADS) {
            int n = i / BK, kk = i % BK;
            int gn = block_n + n, gk = k0 + kk;
            Bs[kk][n] = (gn < N && gk < K) ? B[(size_t)gn * ldb + gk] : 0.f;
        }
        __syncthreads();
#pragma unroll
        for (int kk = 0; kk < BK; kk++) {
            float a[TM], b[TN];
#pragma unroll
            for (int i = 0; i < TM; i++) a[i] = As[kk][ty * TM + i];
#pragma unroll
            for (int j = 0; j < TN; j++) b[j] = Bs[kk][tx * TN + j];
#pragma unroll
            for (int i = 0; i < TM; i++)
#pragma unroll
                for (int j = 0; j < TN; j++) acc[i][j] += a[i] * b[j];
        }
        __syncthreads();
    }
#pragma unroll
    for (int i = 0; i < TM; i++) {
        int gm = block_m + ty * TM + i;
        if (gm >= M) continue;
#pragma unroll
        for (int j = 0; j < TN; j++) {
            int gn = block_n + tx * TN + j;
            if (gn >= N) continue;
            float v = acc[i][j];
            if (bias1) v += bias1[gn];
            if (bias2) v += bias2[gn];
            if (RELU) v = fmaxf(v, 0.f);
            C[(size_t)gm * ldc + gn] = v;
        }
    }
}

// ---------------------------------------------------------------------------
// LSTM pointwise
// ---------------------------------------------------------------------------
__global__ void lstm_pointwise(const float* __restrict__ xW, const float* __restrict__ gt,
                               float* __restrict__ h, float* __restrict__ c,
                               float* __restrict__ hs, int t) {
    int idx = blockIdx.x * blockDim.x + threadIdx.x;
    if (idx >= BB * HH) return;
    int b = idx >> 10, hh = idx & (HH - 1);
    size_t rx = ((size_t)b * TT + t) * 4 * HH;
    size_t rg = (size_t)b * 4 * HH;
    float gi = xW[rx + hh] + gt[rg + hh];
    float gf = xW[rx + HH + hh] + gt[rg + HH + hh];
    float gg = xW[rx + 2 * HH + hh] + gt[rg + 2 * HH + hh];
    float go = xW[rx + 3 * HH + hh] + gt[rg + 3 * HH + hh];
    float si = 1.f / (1.f + expf(-gi));
    float sf = 1.f / (1.f + expf(-gf));
    float so = 1.f / (1.f + expf(-go));
    float tg = tanhf(gg);
    float cn = sf * c[idx] + si * tg;
    float hn = so * tanhf(cn);
    c[idx] = cn;
    h[idx] = hn;
    hs[((size_t)t * BB + b) * HH + hh] = hn;
}

__global__ void qa2_kernel(const float* __restrict__ qa, const float* __restrict__ Wq2,
                           const float* __restrict__ bq2, float* __restrict__ out) {
    int tid = blockIdx.x * blockDim.x + threadIdx.x;
    if (tid >= BB * 2 * TT) return;
    int t = tid % TT;
    int bg = tid / TT;
    int g = bg & 1;
    const float* arow = qa + ((size_t)t * BB + (bg >> 1)) * 512;
    const float* wrow = Wq2 + g * 512;
    float acc = bq2[g];
    for (int o = 0; o < 512; o++) acc += wrow[o] * arow[o];
    out[tid] = acc;
}

__global__ void ia2_kernel(const float* __restrict__ ia, const float* __restrict__ Wi2,
                           const float* __restrict__ bi2, float* __restrict__ out) {
    int tid = blockIdx.x * blockDim.x + threadIdx.x;
    if (tid >= BB * 2 * SS) return;
    int s = tid % SS;
    int bg = tid / SS;
    int g = bg & 1;
    int b = bg >> 1;
    const float* arow = ia + ((size_t)b * SS + s) * 512;
    const float* wrow = Wi2 + g * 512;
    float acc = bi2[g];
    for (int o = 0; o < 512; o++) acc += wrow[o] * arow[o];
    out[tid] = acc;
}

__global__ void softmax_small(float* __restrict__ x, int rows, int len) {
    int r = blockIdx.x * blockDim.x + threadIdx.x;
    if (r >= rows) return;
    float* xr = x + (size_t)r * len;
    float mx = -1e30f;
    for (int i = 0; i < len; i++) mx = fmaxf(mx, xr[i]);
    float s = 0.f;
    for (int i = 0; i < len; i++) s += expf(xr[i] - mx);
    float inv = 1.f / s;
    for (int i = 0; i < len; i++) xr[i] = expf(xr[i] - mx) * inv;
}

__global__ void qfeat_kernel(const float* __restrict__ qatt, const float* __restrict__ hs,
                             float* __restrict__ qf) {
    int idx = blockIdx.x * blockDim.x + threadIdx.x;
    if (idx >= BB * 2048) return;
    int b = idx >> 11;
    int gh = idx & 2047;
    int g = gh >> 10;
    int hh = gh & 1023;
    float acc = 0.f;
    for (int t = 0; t < TT; t++)
        acc += qatt[((size_t)b * 2 + g) * TT + t] * hs[((size_t)t * BB + b) * HH + hh];
    qf[idx] = acc;
}

// ---------------------------------------------------------------------------
// MCB1 sketch via LDS privatization (no global atomics) + FACTOR fold + pad.
// Block (r, b): owns folded-output bins [r*FOLD_R, r*FOLD_R+FOLD_R) of batch b.
// Needs raw bins [r0, r0+FOLD_R+196) (mod D1) since fold reads t+49f, f<=4.
// ---------------------------------------------------------------------------
__global__ void sketch_fold(const float* __restrict__ img_feat, const int* __restrict__ h1x,
                            const int* __restrict__ s1x, float* __restrict__ aext) {
    __shared__ float sl[FOLD_R + 196];
    const int b = blockIdx.y;
    const int r0 = blockIdx.x * FOLD_R;
    for (int i = threadIdx.x; i < FOLD_R + 196; i += 256) sl[i] = 0.f;
    __syncthreads();
    for (int i = threadIdx.x; i < NITEMS; i += 256) {
        int h = h1x[i];
        int d = h - r0;
        if (d < 0) d += D1;
        if (d < FOLD_R + 196) {
            int f = i / SS, s = i - f * SS;   // item n = f*49 + s
            float val = img_feat[((size_t)b * SS + s) * FEAT + f]
                        * (float)(2 * s1x[i] - 1);
            atomicAdd(&sl[d], val);
        }
    }
    __syncthreads();
    float* ab = aext + (size_t)b * AEXT_STRIDE;
    for (int t = threadIdx.x; t < FOLD_R; t += 256) {
        int g = r0 + t;
        if (g >= D1) break;
        float v = sl[t] + sl[t + 49] + sl[t + 98] + sl[t + 147] + sl[t + 196];
        ab[g] = v;
        if (g < PAD1) ab[D1 + g] = v;   // wraparound pad for mod-free gather
    }
}

// ---------------------------------------------------------------------------
// MCB1 gather conv: iq[b,s,m] = sum_j v_j * atil[b, (245m+s-p_j) mod D1]
// 16 blocks/batch, 12 outputs/thread strided by 256. Pad removes the mod.
// ---------------------------------------------------------------------------
static constexpr int GTILE = 3072;
static constexpr int GK = 12;

__global__ void mcb1_gather2(const float* __restrict__ aext, const float* __restrict__ qf,
                             const int* __restrict__ h1q, const int* __restrict__ s1q,
                             float* __restrict__ iq) {
    __shared__ int sp[2048];
    __shared__ float sv[2048];
    const int b = blockIdx.y;
    const float* __restrict__ ab = aext + (size_t)b * AEXT_STRIDE;
    const float* qb = qf + (size_t)b * 2048;
    for (int j = threadIdx.x; j < 2048; j += 256) {
        sp[j] = h1q[j];
        sv[j] = qb[j] * (float)(2 * s1q[j] - 1);
    }
    __syncthreads();
    const int o0 = blockIdx.x * GTILE + threadIdx.x;
    int tb[GK];
    float acc[GK];
#pragma unroll
    for (int k = 0; k < GK; k++) {
        int o = o0 + 256 * k;
        int oo = (o < MOUT * SS) ? o : MOUT * SS - 1;   // clamp keeps loads in-range
        int m = oo / SS;
        tb[k] = 245 * m + (oo - m * SS);
        acc[k] = 0.f;
    }
    const int tb0 = tb[0];
    for (int j = 0; j < 2048; j++) {
        int p = sp[j];
        float v = sv[j];
        unsigned qe = (unsigned)((p <= tb0) ? -p : D1 - p);
#pragma unroll
        for (int k = 0; k < GK; k++) acc[k] += v * ab[(unsigned)tb[k] + qe];
    }
#pragma unroll
    for (int k = 0; k < GK; k++) {
        int o = o0 + 256 * k;
        if (o < MOUT * SS) {
            int m = o / SS, s = o - m * SS;
            iq[((size_t)b * SS + s) * MOUT + m] = acc[k];
        }
    }
}

__global__ void ssqrt_l2norm(float* __restrict__ x, int n) {
    __shared__ float red[256];
    __shared__ float inv_s;
    int b = blockIdx.x;
    float* xb = x + (size_t)b * n;
    float ss = 0.f;
    for (int i = threadIdx.x; i < n; i += 256) {
        float v = xb[i];
        float y = (v >= 0.f) ? sqrtf(v) : -sqrtf(-v);
        xb[i] = y;
        ss += y * y;
    }
    red[threadIdx.x] = ss;
    __syncthreads();
    for (int s = 128; s > 0; s >>= 1) {
        if (threadIdx.x < s) red[threadIdx.x] += red[threadIdx.x + s];
        __syncthreads();
    }
    if (threadIdx.x == 0) inv_s = 1.f / fmaxf(sqrtf(red[0]), 1e-12f);
    __syncthreads();
    float inv = inv_s;
    for (int i = threadIdx.x; i < n; i += 256) xb[i] *= inv;
}

__global__ void ifeat_kernel(const float* __restrict__ iatt, const float* __restrict__ img_feat,
                             float* __restrict__ ifeat) {
    int idx = blockIdx.x * blockDim.x + threadIdx.x;
    if (idx >= BB * 4096) return;
    int b = idx >> 12;
    int gf = idx & 4095;
    int g = gf >> 11;
    int f = gf & 2047;
    float acc = 0.f;
    for (int s = 0; s < SS; s++)
        acc += iatt[((size_t)b * 2 + g) * SS + s] * img_feat[((size_t)b * SS + s) * FEAT + f];
    ifeat[idx] = acc;
}

__global__ void mcb2_scatter(const float* __restrict__ ifeat, const int* __restrict__ h2i,
                             const int* __restrict__ s2i, float* __restrict__ atil2) {
    int tid = blockIdx.x * blockDim.x + threadIdx.x;
    if (tid >= BB * 4096) return;
    int i = tid & 4095;
    int b = tid >> 12;
    float v = ifeat[tid] * (float)(2 * s2i[i] - 1);
    int p = h2i[i];
    float* ab = atil2 + (size_t)b * D2;
#pragma unroll
    for (int f = 0; f < 5; f++) {
        int t = p - f;
        if (t < 0) t += D2;
        atomicAdd(&ab[t], v);
    }
}

__global__ void mcb2_gather(const float* __restrict__ atil2, const float* __restrict__ qf,
                            const int* __restrict__ h2q, const int* __restrict__ s2q,
                            float* __restrict__ z) {
    __shared__ float sa[D2];
    __shared__ int sp[2048];
    __shared__ float sv[2048];
    int b = blockIdx.y;
    for (int i = threadIdx.x; i < D2; i += 256) sa[i] = atil2[(size_t)b * D2 + i];
    const float* qb = qf + (size_t)b * 2048;
    for (int j = threadIdx.x; j < 2048; j += 256) {
        sp[j] = h2q[j];
        sv[j] = qb[j] * (float)(2 * s2q[j] - 1);
    }
    __syncthreads();
    int m = blockIdx.x * 256 + threadIdx.x;
    if (m >= MOUT) return;
    int base = 5 * m + D2;
    float acc = 0.f;
#pragma unroll 4
    for (int j = 0; j < 2048; j++) {
        int addr = base - sp[j];
        if (addr >= D2) addr -= D2;
        acc += sv[j] * sa[addr];
    }
    z[(size_t)b * MOUT + m] = acc;
}

__global__ void softmax_rows(const float* __restrict__ logits, float* __restrict__ out, int n) {
    __shared__ float red[256];
    int b = blockIdx.x;
    const float* xr = logits + (size_t)b * n;
    float* orow = out + (size_t)b * n;
    float mx = -1e30f;
    for (int i = threadIdx.x; i < n; i += 256) mx = fmaxf(mx, xr[i]);
    red[threadIdx.x] = mx;
    __syncthreads();
    for (int s = 128; s > 0; s >>= 1) {
        if (threadIdx.x < s) red[threadIdx.x] = fmaxf(red[threadIdx.x], red[threadIdx.x + s]);
        __syncthreads();
    }
    mx = red[0];
    __syncthreads();
    float sum = 0.f;
    for (int i = threadIdx.x; i < n; i += 256) sum += expf(xr[i] - mx);
    red[threadIdx.x] = sum;
    __syncthreads();
    for (int s = 128; s > 0; s >>= 1) {
        if (threadIdx.x < s) red[threadIdx.x] += red[threadIdx.x + s];
        __syncthreads();
    }
    float inv = 1.f / red[0];
    for (int i = threadIdx.x; i < n; i += 256) orow[i] = expf(xr[i] - mx) * inv;
}

extern "C" void kernel_launch(void* const* d_in, const int* in_sizes, int n_in,
                              void* d_out, int out_size, void* d_ws, size_t ws_size,
                              hipStream_t stream) {
    (void)in_sizes; (void)n_in; (void)out_size; (void)ws_size;
    const float* ques = (const float*)d_in[0];
    const float* img  = (const float*)d_in[1];
    const float* W_ih = (const float*)d_in[2];
    const float* W_hh = (const float*)d_in[3];
    const float* b_ih = (const float*)d_in[4];
    const float* b_hh = (const float*)d_in[5];
    const float* Wq1  = (const float*)d_in[6];
    const float* bq1  = (const float*)d_in[7];
    const float* Wq2  = (const float*)d_in[8];
    const float* bq2  = (const float*)d_in[9];
    const float* Wi1  = (const float*)d_in[10];
    const float* bi1  = (const float*)d_in[11];
    const float* Wi2  = (const float*)d_in[12];
    const float* bi2  = (const float*)d_in[13];
    const float* Wp   = (const float*)d_in[14];
    const float* bp   = (const float*)d_in[15];
    const int* h1x = (const int*)d_in[16];
    const int* s1x = (const int*)d_in[17];
    const int* h1q = (const int*)d_in[18];
    const int* s1q = (const int*)d_in[19];
    const int* h2i = (const int*)d_in[20];
    const int* s2i = (const int*)d_in[21];
    const int* h2q = (const int*)d_in[22];
    const int* s2q = (const int*)d_in[23];
    float* out = (float*)d_out;

    // workspace layout (floats), two-phase overlap. Total 22,320,640 f = 89.3 MB.
    float* ws = (float*)d_ws;
    float* aext = ws;                         // 64*259400 = 16,601,600 (phase2)
    float* xw   = ws;                         // 26*64*4096 = 6,815,744 (phase1, aliases aext)
    float* qf   = ws + 16601600;              // 131,072 (persistent)
    float* sh   = ws + 16601600 + 131072;     // shared union region
    // phase 1 (LSTM + question attention)
    float* hs   = sh;                         // 1,703,936
    float* hcur = sh + 1703936;               // 65,536
    float* ccur = sh + 1769472;               // 65,536
    float* gt   = sh + 1835008;               // 262,144
    float* qa   = sh + 2097152;               // 851,968
    float* qatt = sh + 2949120;               // 4,096
    // phase 2 (image path; phase-1 buffers dead by first write)
    float* iq     = sh;                       // 3,136,000
    float* ia     = sh + 3136000;             // 1,605,632
    float* iatt   = sh + 4741632;             // 8,192
    float* ifeat  = sh + 4749824;             // 262,144
    float* atil2  = sh + 5011968;             // 320,000
    float* z      = sh + 5331968;             // 64,000
    float* logits = sh + 5395968;             // 192,000

    // ---- LSTM ----
    hipMemsetAsync(hcur, 0, (size_t)BB * HH * 4, stream);
    hipMemsetAsync(ccur, 0, (size_t)BB * HH * 4, stream);
    {
        dim3 grid(4096 / 64, (BB * TT + 63) / 64);
        gemm_abt<64, 64, 16, 4, 4, false><<<grid, 256, 0, stream>>>(
            ques, W_ih, b_ih, b_hh, xw, BB * TT, 4 * HH, EE, EE, EE, 4 * HH);
    }
    for (int t = 0; t < TT; t++) {
        dim3 grid(4096 / 64, 4);
        gemm_abt<16, 64, 16, 2, 2, false><<<grid, 256, 0, stream>>>(
            hcur, W_hh, nullptr, nullptr, gt, BB, 4 * HH, HH, HH, HH, 4 * HH);
        lstm_pointwise<<<(BB * HH + 255) / 256, 256, 0, stream>>>(xw, gt, hcur, ccur, hs, t);
    }
    // ---- question attention ----
    {
        dim3 grid(512 / 64, (TT * BB) / 64);
        gemm_abt<64, 64, 16, 4, 4, true><<<grid, 256, 0, stream>>>(
            hs, Wq1, bq1, nullptr, qa, TT * BB, 512, HH, HH, HH, 512);
    }
    qa2_kernel<<<(BB * 2 * TT + 255) / 256, 256, 0, stream>>>(qa, Wq2, bq2, qatt);
    softmax_small<<<1, 128, 0, stream>>>(qatt, BB * 2, TT);
    qfeat_kernel<<<(BB * 2048) / 256, 256, 0, stream>>>(qatt, hs, qf);
    // ---- MCB1 sketch (LDS-privatized, folded, padded) + image attention ----
    {
        dim3 grid(FOLD_NR, BB);
        sketch_fold<<<grid, 256, 0, stream>>>(img, h1x, s1x, aext);
    }
    {
        dim3 grid(16, BB);
        mcb1_gather2<<<grid, 256, 0, stream>>>(aext, qf, h1q, s1q, iq);
    }
    ssqrt_l2norm<<<BB, 256, 0, stream>>>(iq, MOUT * SS);
    {
        dim3 grid(512 / 64, (BB * SS + 63) / 64);
        gemm_abt<64, 64, 16, 4, 4, true><<<grid, 256, 0, stream>>>(
            iq, Wi1, bi1, nullptr, ia, BB * SS, 512, MOUT, MOUT, MOUT, 512);
    }
    ia2_kernel<<<(BB * 2 * SS + 255) / 256, 256, 0, stream>>>(ia, Wi2, bi2, iatt);
    softmax_small<<<1, 128, 0, stream>>>(iatt, BB * 2, SS);
    ifeat_kernel<<<(BB * 4096) / 256, 256, 0, stream>>>(iatt, img, ifeat);
    // ---- MCB2 + classifier ----
    hipMemsetAsync(atil2, 0, (size_t)BB * D2 * 4, stream);
    mcb2_scatter<<<(BB * 4096) / 256, 256, 0, stream>>>(ifeat, h2i, s2i, atil2);
    {
        dim3 grid(4, BB);
        mcb2_gather<<<grid, 256, 0, stream>>>(atil2, qf, h2q, s2q, z);
    }
    ssqrt_l2norm<<<BB, 256, 0, stream>>>(z, MOUT);
    {
        dim3 grid((VOCAB + 63) / 64, 4);
        gemm_abt<16, 64, 16, 2, 2, false><<<grid, 256, 0, stream>>>(
            z, Wp, bp, nullptr, logits, BB, VOCAB, MOUT, MOUT, MOUT, VOCAB);
    }
    softmax_rows<<<BB, 256, 0, stream>>>(logits, out, VOCAB);
}

// Round 3
// 4625.203 us; speedup vs baseline: 2.0378x; 2.0378x over previous
//
#include <hip/hip_runtime.h>
#include <math.h>

// Problem constants
static constexpr int BB = 64, TT = 26, EE = 300, HH = 1024;
static constexpr int FEAT = 2048, SS = 49;
static constexpr int D1 = 245000, D2 = 5000;
static constexpr int MOUT = 1000;
static constexpr int VOCAB = 3000;

static constexpr int PAD1T = 2048;               // mod-free pad rows (span <= 245*7+1 = 1716)
static constexpr int NROWS = D1 + PAD1T;         // 247048 rows in transposed sketch
static constexpr int FOLD_R = 16000;
static constexpr int FOLD_NR = 16;
static constexpr int NITEMS = FEAT * SS;         // 100352
static constexpr int NP = 10;                    // gather phases
static constexpr int WP = 24500;                 // phase window (bins); WP*NP = D1

// ---------------------------------------------------------------------------
// Generic fp32 GEMM: C[M,N] = act( A(M,K) * B(N,K)^T + bias1 + bias2 )
// ---------------------------------------------------------------------------
template <int BM, int BN, int BK, int TM, int TN, bool RELU>
__global__ void gemm_abt(const float* __restrict__ A, const float* __restrict__ B,
                         const float* __restrict__ bias1, const float* __restrict__ bias2,
                         float* __restrict__ C,
                         int M, int N, int K, int lda, int ldb, int ldc) {
    constexpr int THREADS = (BM / TM) * (BN / TN);
    __shared__ float As[BK][BM + 1];
    __shared__ float Bs[BK][BN + 1];
    const int tid = threadIdx.x;
    const int tx = tid % (BN / TN);
    const int ty = tid / (BN / TN);
    const int block_m = blockIdx.y * BM;
    const int block_n = blockIdx.x * BN;
    float acc[TM][TN];
#pragma unroll
    for (int i = 0; i < TM; i++)
#pragma unroll
        for (int j = 0; j < TN; j++) acc[i][j] = 0.f;

    for (int k0 = 0; k0 < K; k0 += BK) {
        for (int i = tid; i < BM * BK; i += THREADS) {
            int m = i / BK, kk = i % BK;
            int gm = block_m + m, gk = k0 + kk;
            As[kk][m] = (gm < M && gk < K) ? A[(size_t)gm * lda + gk] : 0.f;
        }
        for (int i = tid; i < BN * BK; i += THREADS) {
            int n = i / BK, kk = i % BK;
            int gn = block_n + n, gk = k0 + kk;
            Bs[kk][n] = (gn < N && gk < K) ? B[(size_t)gn * ldb + gk] : 0.f;
        }
        __syncthreads();
#pragma unroll
        for (int kk = 0; kk < BK; kk++) {
            float a[TM], b[TN];
#pragma unroll
            for (int i = 0; i < TM; i++) a[i] = As[kk][ty * TM + i];
#pragma unroll
            for (int j = 0; j < TN; j++) b[j] = Bs[kk][tx * TN + j];
#pragma unroll
            for (int i = 0; i < TM; i++)
#pragma unroll
                for (int j = 0; j < TN; j++) acc[i][j] += a[i] * b[j];
        }
        __syncthreads();
    }
#pragma unroll
    for (int i = 0; i < TM; i++) {
        int gm = block_m + ty * TM + i;
        if (gm >= M) continue;
#pragma unroll
        for (int j = 0; j < TN; j++) {
            int gn = block_n + tx * TN + j;
            if (gn >= N) continue;
            float v = acc[i][j];
            if (bias1) v += bias1[gn];
            if (bias2) v += bias2[gn];
            if (RELU) v = fmaxf(v, 0.f);
            C[(size_t)gm * ldc + gn] = v;
        }
    }
}

// ---------------------------------------------------------------------------
// LSTM pointwise
// ---------------------------------------------------------------------------
__global__ void lstm_pointwise(const float* __restrict__ xW, const float* __restrict__ gt,
                               float* __restrict__ h, float* __restrict__ c,
                               float* __restrict__ hs, int t) {
    int idx = blockIdx.x * blockDim.x + threadIdx.x;
    if (idx >= BB * HH) return;
    int b = idx >> 10, hh = idx & (HH - 1);
    size_t rx = ((size_t)b * TT + t) * 4 * HH;
    size_t rg = (size_t)b * 4 * HH;
    float gi = xW[rx + hh] + gt[rg + hh];
    float gf = xW[rx + HH + hh] + gt[rg + HH + hh];
    float gg = xW[rx + 2 * HH + hh] + gt[rg + 2 * HH + hh];
    float go = xW[rx + 3 * HH + hh] + gt[rg + 3 * HH + hh];
    float si = 1.f / (1.f + expf(-gi));
    float sf = 1.f / (1.f + expf(-gf));
    float so = 1.f / (1.f + expf(-go));
    float tg = tanhf(gg);
    float cn = sf * c[idx] + si * tg;
    float hn = so * tanhf(cn);
    c[idx] = cn;
    h[idx] = hn;
    hs[((size_t)t * BB + b) * HH + hh] = hn;
}

__global__ void qa2_kernel(const float* __restrict__ qa, const float* __restrict__ Wq2,
                           const float* __restrict__ bq2, float* __restrict__ out) {
    int tid = blockIdx.x * blockDim.x + threadIdx.x;
    if (tid >= BB * 2 * TT) return;
    int t = tid % TT;
    int bg = tid / TT;
    int g = bg & 1;
    const float* arow = qa + ((size_t)t * BB + (bg >> 1)) * 512;
    const float* wrow = Wq2 + g * 512;
    float acc = bq2[g];
    for (int o = 0; o < 512; o++) acc += wrow[o] * arow[o];
    out[tid] = acc;
}

__global__ void ia2_kernel(const float* __restrict__ ia, const float* __restrict__ Wi2,
                           const float* __restrict__ bi2, float* __restrict__ out) {
    int tid = blockIdx.x * blockDim.x + threadIdx.x;
    if (tid >= BB * 2 * SS) return;
    int s = tid % SS;
    int bg = tid / SS;
    int g = bg & 1;
    int b = bg >> 1;
    const float* arow = ia + ((size_t)b * SS + s) * 512;
    const float* wrow = Wi2 + g * 512;
    float acc = bi2[g];
    for (int o = 0; o < 512; o++) acc += wrow[o] * arow[o];
    out[tid] = acc;
}

__global__ void softmax_small(float* __restrict__ x, int rows, int len) {
    int r = blockIdx.x * blockDim.x + threadIdx.x;
    if (r >= rows) return;
    float* xr = x + (size_t)r * len;
    float mx = -1e30f;
    for (int i = 0; i < len; i++) mx = fmaxf(mx, xr[i]);
    float s = 0.f;
    for (int i = 0; i < len; i++) s += expf(xr[i] - mx);
    float inv = 1.f / s;
    for (int i = 0; i < len; i++) xr[i] = expf(xr[i] - mx) * inv;
}

__global__ void qfeat_kernel(const float* __restrict__ qatt, const float* __restrict__ hs,
                             float* __restrict__ qf) {
    int idx = blockIdx.x * blockDim.x + threadIdx.x;
    if (idx >= BB * 2048) return;
    int b = idx >> 11;
    int gh = idx & 2047;
    int g = gh >> 10;
    int hh = gh & 1023;
    float acc = 0.f;
    for (int t = 0; t < TT; t++)
        acc += qatt[((size_t)b * 2 + g) * TT + t] * hs[((size_t)t * BB + b) * HH + hh];
    qf[idx] = acc;
}

// ---------------------------------------------------------------------------
// MCB1 stage A: LDS-privatized scatter + FACTOR fold -> afold[b][t] fp32
// ---------------------------------------------------------------------------
__global__ void sketch_fold(const float* __restrict__ img_feat, const int* __restrict__ h1x,
                            const int* __restrict__ s1x, float* __restrict__ afold) {
    __shared__ float sl[FOLD_R + 196];
    const int b = blockIdx.y;
    const int r0 = blockIdx.x * FOLD_R;
    for (int i = threadIdx.x; i < FOLD_R + 196; i += 256) sl[i] = 0.f;
    __syncthreads();
    for (int i = threadIdx.x; i < NITEMS; i += 256) {
        int h = h1x[i];
        int d = h - r0;
        if (d < 0) d += D1;
        if (d < FOLD_R + 196) {
            int f = i / SS, s = i - f * SS;
            float val = img_feat[((size_t)b * SS + s) * FEAT + f]
                        * (float)(2 * s1x[i] - 1);
            atomicAdd(&sl[d], val);
        }
    }
    __syncthreads();
    float* ab = afold + (size_t)b * D1;
    for (int t = threadIdx.x; t < FOLD_R; t += 256) {
        int g = r0 + t;
        if (g >= D1) break;
        ab[g] = sl[t] + sl[t + 49] + sl[t + 98] + sl[t + 147] + sl[t + 196];
    }
}

__device__ __forceinline__ unsigned short bf16_rne(float x) {
    unsigned u = __float_as_uint(x);
    u += 0x7fffu + ((u >> 16) & 1u);
    return (unsigned short)(u >> 16);
}

// ---------------------------------------------------------------------------
// MCB1 stage B: transpose afold[b][t] -> atT[t][32 x bf16x2], with wrap pad.
// Tile 64 t x 64 b via LDS.
// ---------------------------------------------------------------------------
__global__ void transpose_bf16(const float* __restrict__ afold, unsigned* __restrict__ atT) {
    __shared__ float L[64][65];
    const int t0 = blockIdx.x * 64;
    const int tid = threadIdx.x;
    for (int c = 0; c < 16; c++) {
        int idx = c * 256 + tid;          // b*64 + i
        int b = idx >> 6, i = idx & 63;
        int t = t0 + i;
        int src_t = (t < D1) ? t : t - D1;
        L[i][b] = afold[(size_t)b * D1 + src_t];
    }
    __syncthreads();
    for (int c = 0; c < 8; c++) {
        int u = c * 256 + tid;            // t_loc*32 + qq
        int t_loc = u >> 5, qq = u & 31;
        int t = t0 + t_loc;
        if (t >= NROWS) continue;
        unsigned lo = bf16_rne(L[t_loc][2 * qq]);
        unsigned hi = bf16_rne(L[t_loc][2 * qq + 1]);
        atT[(size_t)t * 32 + qq] = lo | (hi << 16);
    }
}

// ---------------------------------------------------------------------------
// Bitonic sort of (h1q, index), 2048 elements, one block of 1024 threads.
// ---------------------------------------------------------------------------
__global__ void sort_pv(const int* __restrict__ h1q, int* __restrict__ pS,
                        int* __restrict__ permS) {
    __shared__ int k[2048], v[2048];
    const int t = threadIdx.x;
    k[t] = h1q[t];          v[t] = t;
    k[t + 1024] = h1q[t + 1024]; v[t + 1024] = t + 1024;
    for (int size = 2; size <= 2048; size <<= 1) {
        for (int stride = size >> 1; stride > 0; stride >>= 1) {
            __syncthreads();
            int pos = 2 * t - (t & (stride - 1));
            bool asc = ((pos & size) == 0);
            int a = k[pos], b = k[pos + stride];
            if ((a > b) == asc) {
                k[pos] = b; k[pos + stride] = a;
                int tmp = v[pos]; v[pos] = v[pos + stride]; v[pos + stride] = tmp;
            }
        }
    }
    __syncthreads();
    pS[t] = k[t]; pS[t + 1024] = k[t + 1024];
    permS[t] = v[t]; permS[t + 1024] = v[t + 1024];
}

// vTs[r][q] = pack_bf16( qf[2q][j]*sgn[j], qf[2q+1][j]*sgn[j] ), j = permS[r]
__global__ void vts_build(const float* __restrict__ qf, const int* __restrict__ s1q,
                          const int* __restrict__ permS, unsigned* __restrict__ vTs) {
    int gid = blockIdx.x * blockDim.x + threadIdx.x;
    if (gid >= 2048 * 32) return;
    int r = gid >> 5, q = gid & 31;
    int j = permS[r];
    float sg = (float)(2 * s1q[j] - 1);
    unsigned lo = bf16_rne(qf[(size_t)(2 * q) * 2048 + j] * sg);
    unsigned hi = bf16_rne(qf[(size_t)(2 * q + 1) * 2048 + j] * sg);
    vTs[gid] = lo | (hi << 16);
}

__device__ __forceinline__ int lbound(const int* a, int x) {
    int lo = 0, hi = 2048;
    while (lo < hi) { int mid = (lo + hi) >> 1; if (a[mid] < x) lo = mid + 1; else hi = mid; }
    return lo;
}

// ---------------------------------------------------------------------------
// MCB1 gather, batch-major bf16, phase-partitioned for L2 residency.
// Block (mtile, s): 64 m-values; thread (w=tid/32, q=tid%32): 8 m, batch pair 2q/2q+1.
// iq[b][s][m] (fp32) = sum_j v[b,j] * sketch[(245m+s-p_j) mod D1]
// ---------------------------------------------------------------------------
__global__ void __launch_bounds__(256, 8)
mcb1_gather3(const unsigned* __restrict__ atT, const unsigned* __restrict__ vTs,
             const int* __restrict__ pS, float* __restrict__ iq) {
    __shared__ int sp[2048];
    for (int i = threadIdx.x; i < 2048; i += 256) sp[i] = pS[i];
    __syncthreads();

    const int s = blockIdx.y;
    const int w = threadIdx.x >> 5;
    const int q = threadIdx.x & 31;
    const int m0 = blockIdx.x * 64 + w * 8;
    const int m0c = (m0 <= 992) ? m0 : 992;
    const int tb0 = 245 * m0c + s;

    const unsigned* __restrict__ atq = atT + q;
    const unsigned* __restrict__ vtq = vTs + q;

    float accL[8], accH[8];
#pragma unroll
    for (int kk = 0; kk < 8; kk++) { accL[kk] = 0.f; accH[kk] = 0.f; }

    for (int c = 0; c < NP; c++) {
        const int A0 = c * WP;
        const int A1 = A0 + WP;
        int PL = tb0 - A1 + 1; if (PL < 0) PL += D1; if (PL >= D1) PL -= D1;
        int PH = tb0 - A0;     if (PH < 0) PH += D1; if (PH >= D1) PH -= D1;
        int r0a, r1a, r0b, r1b;
        if (PL <= PH) {
            r0a = lbound(sp, PL); r1a = lbound(sp, PH + 1);
            r0b = 0; r1b = 0;
        } else {
            r0a = lbound(sp, PL); r1a = 2048;
            r0b = 0; r1b = lbound(sp, PH + 1);
        }
#pragma unroll 1
        for (int seg = 0; seg < 2; seg++) {
            int rs = seg ? r0b : r0a;
            int re = seg ? r1b : r1a;
            for (int r = rs; r < re; r++) {
                int p = sp[r];
                int qe = (p <= tb0) ? -p : D1 - p;
                unsigned vv = vtq[r * 32];
                float vlo = __uint_as_float(vv << 16);
                float vhi = __uint_as_float(vv & 0xffff0000u);
                const unsigned* row = atq + (size_t)(tb0 + qe) * 32;
#pragma unroll
                for (int kk = 0; kk < 8; kk++) {
                    unsigned u = row[kk * 245 * 32];
                    float alo = __uint_as_float(u << 16);
                    float ahi = __uint_as_float(u & 0xffff0000u);
                    accL[kk] = fmaf(vlo, alo, accL[kk]);
                    accH[kk] = fmaf(vhi, ahi, accH[kk]);
                }
            }
        }
    }

    if (m0 <= 992) {
        float* o0 = iq + ((size_t)(2 * q) * SS + s) * MOUT + m0;
        float* o1 = iq + ((size_t)(2 * q + 1) * SS + s) * MOUT + m0;
#pragma unroll
        for (int kk = 0; kk < 8; kk++) { o0[kk] = accL[kk]; o1[kk] = accH[kk]; }
    }
}

__global__ void ssqrt_l2norm(float* __restrict__ x, int n) {
    __shared__ float red[256];
    __shared__ float inv_s;
    int b = blockIdx.x;
    float* xb = x + (size_t)b * n;
    float ss = 0.f;
    for (int i = threadIdx.x; i < n; i += 256) {
        float v = xb[i];
        float y = (v >= 0.f) ? sqrtf(v) : -sqrtf(-v);
        xb[i] = y;
        ss += y * y;
    }
    red[threadIdx.x] = ss;
    __syncthreads();
    for (int s = 128; s > 0; s >>= 1) {
        if (threadIdx.x < s) red[threadIdx.x] += red[threadIdx.x + s];
        __syncthreads();
    }
    if (threadIdx.x == 0) inv_s = 1.f / fmaxf(sqrtf(red[0]), 1e-12f);
    __syncthreads();
    float inv = inv_s;
    for (int i = threadIdx.x; i < n; i += 256) xb[i] *= inv;
}

__global__ void ifeat_kernel(const float* __restrict__ iatt, const float* __restrict__ img_feat,
                             float* __restrict__ ifeat) {
    int idx = blockIdx.x * blockDim.x + threadIdx.x;
    if (idx >= BB * 4096) return;
    int b = idx >> 12;
    int gf = idx & 4095;
    int g = gf >> 11;
    int f = gf & 2047;
    float acc = 0.f;
    for (int s = 0; s < SS; s++)
        acc += iatt[((size_t)b * 2 + g) * SS + s] * img_feat[((size_t)b * SS + s) * FEAT + f];
    ifeat[idx] = acc;
}

__global__ void mcb2_scatter(const float* __restrict__ ifeat, const int* __restrict__ h2i,
                             const int* __restrict__ s2i, float* __restrict__ atil2) {
    int tid = blockIdx.x * blockDim.x + threadIdx.x;
    if (tid >= BB * 4096) return;
    int i = tid & 4095;
    int b = tid >> 12;
    float v = ifeat[tid] * (float)(2 * s2i[i] - 1);
    int p = h2i[i];
    float* ab = atil2 + (size_t)b * D2;
#pragma unroll
    for (int f = 0; f < 5; f++) {
        int t = p - f;
        if (t < 0) t += D2;
        atomicAdd(&ab[t], v);
    }
}

__global__ void mcb2_gather(const float* __restrict__ atil2, const float* __restrict__ qf,
                            const int* __restrict__ h2q, const int* __restrict__ s2q,
                            float* __restrict__ z) {
    __shared__ float sa[D2];
    __shared__ int sp[2048];
    __shared__ float sv[2048];
    int b = blockIdx.y;
    for (int i = threadIdx.x; i < D2; i += 256) sa[i] = atil2[(size_t)b * D2 + i];
    const float* qb = qf + (size_t)b * 2048;
    for (int j = threadIdx.x; j < 2048; j += 256) {
        sp[j] = h2q[j];
        sv[j] = qb[j] * (float)(2 * s2q[j] - 1);
    }
    __syncthreads();
    int m = blockIdx.x * 256 + threadIdx.x;
    if (m >= MOUT) return;
    int base = 5 * m + D2;
    float acc = 0.f;
#pragma unroll 4
    for (int j = 0; j < 2048; j++) {
        int addr = base - sp[j];
        if (addr >= D2) addr -= D2;
        acc += sv[j] * sa[addr];
    }
    z[(size_t)b * MOUT + m] = acc;
}

__global__ void softmax_rows(const float* __restrict__ logits, float* __restrict__ out, int n) {
    __shared__ float red[256];
    int b = blockIdx.x;
    const float* xr = logits + (size_t)b * n;
    float* orow = out + (size_t)b * n;
    float mx = -1e30f;
    for (int i = threadIdx.x; i < n; i += 256) mx = fmaxf(mx, xr[i]);
    red[threadIdx.x] = mx;
    __syncthreads();
    for (int s = 128; s > 0; s >>= 1) {
        if (threadIdx.x < s) red[threadIdx.x] = fmaxf(red[threadIdx.x], red[threadIdx.x + s]);
        __syncthreads();
    }
    mx = red[0];
    __syncthreads();
    float sum = 0.f;
    for (int i = threadIdx.x; i < n; i += 256) sum += expf(xr[i] - mx);
    red[threadIdx.x] = sum;
    __syncthreads();
    for (int s = 128; s > 0; s >>= 1) {
        if (threadIdx.x < s) red[threadIdx.x] += red[threadIdx.x + s];
        __syncthreads();
    }
    float inv = 1.f / red[0];
    for (int i = threadIdx.x; i < n; i += 256) orow[i] = expf(xr[i] - mx) * inv;
}

extern "C" void kernel_launch(void* const* d_in, const int* in_sizes, int n_in,
                              void* d_out, int out_size, void* d_ws, size_t ws_size,
                              hipStream_t stream) {
    (void)in_sizes; (void)n_in; (void)out_size; (void)ws_size;
    const float* ques = (const float*)d_in[0];
    const float* img  = (const float*)d_in[1];
    const float* W_ih = (const float*)d_in[2];
    const float* W_hh = (const float*)d_in[3];
    const float* b_ih = (const float*)d_in[4];
    const float* b_hh = (const float*)d_in[5];
    const float* Wq1  = (const float*)d_in[6];
    const float* bq1  = (const float*)d_in[7];
    const float* Wq2  = (const float*)d_in[8];
    const float* bq2  = (const float*)d_in[9];
    const float* Wi1  = (const float*)d_in[10];
    const float* bi1  = (const float*)d_in[11];
    const float* Wi2  = (const float*)d_in[12];
    const float* bi2  = (const float*)d_in[13];
    const float* Wp   = (const float*)d_in[14];
    const float* bp   = (const float*)d_in[15];
    const int* h1x = (const int*)d_in[16];
    const int* s1x = (const int*)d_in[17];
    const int* h1q = (const int*)d_in[18];
    const int* s1q = (const int*)d_in[19];
    const int* h2i = (const int*)d_in[20];
    const int* s2i = (const int*)d_in[21];
    const int* h2q = (const int*)d_in[22];
    const int* s2q = (const int*)d_in[23];
    float* out = (float*)d_out;

    // Workspace (floats/uints, 4 B units). Total 23,786,240 units = 95.1 MB.
    // Region A (15,680,000): phase1 [xw|hs|hcur|ccur|gt|qa|qatt] -> afold -> phase2 smalls
    float* ws = (float*)d_ws;
    float* xw    = ws;                 // 6,815,744
    float* hs    = ws + 6815744;       // 1,703,936
    float* hcur  = ws + 8519680;       // 65,536
    float* ccur  = ws + 8585216;       // 65,536
    float* gt    = ws + 8650752;       // 262,144
    float* qa    = ws + 8912896;       // 851,968
    float* qatt  = ws + 9764864;       // 4,096
    float* afold = ws;                 // 15,680,000 (overwrites phase1)
    // phase2 smalls (inside region A, alive after transpose)
    float* iq     = ws;                // 3,136,000
    float* ia     = ws + 3136000;      // 1,605,632
    float* iatt   = ws + 4741632;      // 8,192
    float* ifeat  = ws + 4749824;      // 262,144
    float* atil2  = ws + 5011968;      // 320,000
    float* z      = ws + 5331968;      // 64,000
    float* logits = ws + 5395968;      // 192,000
    // Region B/C
    unsigned* atT  = (unsigned*)(ws + 15680000);  // NROWS*32 = 7,905,536
    float* qf      = ws + 15680000 + 7905536;     // 131,072
    unsigned* vTs  = (unsigned*)(qf + 131072);    // 65,536
    int* pS        = (int*)(vTs + 65536);         // 2,048
    int* permS     = pS + 2048;                   // 2,048

    // ---- sort (independent of everything else) ----
    sort_pv<<<1, 1024, 0, stream>>>(h1q, pS, permS);

    // ---- LSTM ----
    hipMemsetAsync(hcur, 0, (size_t)BB * HH * 4, stream);
    hipMemsetAsync(ccur, 0, (size_t)BB * HH * 4, stream);
    {
        dim3 grid(4096 / 64, (BB * TT + 63) / 64);
        gemm_abt<64, 64, 16, 4, 4, false><<<grid, 256, 0, stream>>>(
            ques, W_ih, b_ih, b_hh, xw, BB * TT, 4 * HH, EE, EE, EE, 4 * HH);
    }
    for (int t = 0; t < TT; t++) {
        dim3 grid(4096 / 64, 4);
        gemm_abt<16, 64, 16, 2, 2, false><<<grid, 256, 0, stream>>>(
            hcur, W_hh, nullptr, nullptr, gt, BB, 4 * HH, HH, HH, HH, 4 * HH);
        lstm_pointwise<<<(BB * HH + 255) / 256, 256, 0, stream>>>(xw, gt, hcur, ccur, hs, t);
    }
    // ---- question attention ----
    {
        dim3 grid(512 / 64, (TT * BB) / 64);
        gemm_abt<64, 64, 16, 4, 4, true><<<grid, 256, 0, stream>>>(
            hs, Wq1, bq1, nullptr, qa, TT * BB, 512, HH, HH, HH, 512);
    }
    qa2_kernel<<<(BB * 2 * TT + 255) / 256, 256, 0, stream>>>(qa, Wq2, bq2, qatt);
    softmax_small<<<1, 128, 0, stream>>>(qatt, BB * 2, TT);
    qfeat_kernel<<<(BB * 2048) / 256, 256, 0, stream>>>(qatt, hs, qf);
    // ---- MCB1: fold -> transpose(bf16) -> phased gather ----
    {
        dim3 grid(FOLD_NR, BB);
        sketch_fold<<<grid, 256, 0, stream>>>(img, h1x, s1x, afold);
    }
    {
        int nblk = (NROWS + 63) / 64;
        transpose_bf16<<<nblk, 256, 0, stream>>>(afold, atT);
    }
    vts_build<<<(2048 * 32) / 256, 256, 0, stream>>>(qf, s1q, permS, vTs);
    {
        dim3 grid(16, SS);
        mcb1_gather3<<<grid, 256, 0, stream>>>(atT, vTs, pS, iq);
    }
    ssqrt_l2norm<<<BB, 256, 0, stream>>>(iq, MOUT * SS);
    {
        dim3 grid(512 / 64, (BB * SS + 63) / 64);
        gemm_abt<64, 64, 16, 4, 4, true><<<grid, 256, 0, stream>>>(
            iq, Wi1, bi1, nullptr, ia, BB * SS, 512, MOUT, MOUT, MOUT, 512);
    }
    ia2_kernel<<<(BB * 2 * SS + 255) / 256, 256, 0, stream>>>(ia, Wi2, bi2, iatt);
    softmax_small<<<1, 128, 0, stream>>>(iatt, BB * 2, SS);
    ifeat_kernel<<<(BB * 4096) / 256, 256, 0, stream>>>(iatt, img, ifeat);
    // ---- MCB2 + classifier ----
    hipMemsetAsync(atil2, 0, (size_t)BB * D2 * 4, stream);
    mcb2_scatter<<<(BB * 4096) / 256, 256, 0, stream>>>(ifeat, h2i, s2i, atil2);
    {
        dim3 grid(4, BB);
        mcb2_gather<<<grid, 256, 0, stream>>>(atil2, qf, h2q, s2q, z);
    }
    ssqrt_l2norm<<<BB, 256, 0, stream>>>(z, MOUT);
    {
        dim3 grid((VOCAB + 63) / 64, 4);
        gemm_abt<16, 64, 16, 2, 2, false><<<grid, 256, 0, stream>>>(
            z, Wp, bp, nullptr, logits, BB, VOCAB, MOUT, MOUT, MOUT, VOCAB);
    }
    softmax_rows<<<BB, 256, 0, stream>>>(logits, out, VOCAB);
}

// Round 4
// 4468.942 us; speedup vs baseline: 2.1091x; 1.0350x over previous
//
#include <hip/hip_runtime.h>
#include <math.h>

// Problem constants
static constexpr int BB = 64, TT = 26, EE = 300, HH = 1024;
static constexpr int FEAT = 2048, SS = 49;
static constexpr int D1 = 245000, D2 = 5000;
static constexpr int MOUT = 1000;
static constexpr int VOCAB = 3000;

static constexpr int PAD1T = 2048;               // mod-free pad rows (span <= 245*7+1 = 1716)
static constexpr int NROWS = D1 + PAD1T;         // 247048 rows in transposed sketch
static constexpr int FOLD_R = 16000;
static constexpr int FOLD_NR = 16;
static constexpr int NITEMS = FEAT * SS;         // 100352
static constexpr int NP = 10;                    // gather phases
static constexpr int WP = 24500;                 // phase window (bins); WP*NP = D1

// ---------------------------------------------------------------------------
// Generic fp32 GEMM: C[M,N] = act( A(M,K) * B(N,K)^T + bias1 + bias2 )
// ---------------------------------------------------------------------------
template <int BM, int BN, int BK, int TM, int TN, bool RELU>
__global__ void gemm_abt(const float* __restrict__ A, const float* __restrict__ B,
                         const float* __restrict__ bias1, const float* __restrict__ bias2,
                         float* __restrict__ C,
                         int M, int N, int K, int lda, int ldb, int ldc) {
    constexpr int THREADS = (BM / TM) * (BN / TN);
    __shared__ float As[BK][BM + 1];
    __shared__ float Bs[BK][BN + 1];
    const int tid = threadIdx.x;
    const int tx = tid % (BN / TN);
    const int ty = tid / (BN / TN);
    const int block_m = blockIdx.y * BM;
    const int block_n = blockIdx.x * BN;
    float acc[TM][TN];
#pragma unroll
    for (int i = 0; i < TM; i++)
#pragma unroll
        for (int j = 0; j < TN; j++) acc[i][j] = 0.f;

    for (int k0 = 0; k0 < K; k0 += BK) {
        for (int i = tid; i < BM * BK; i += THREADS) {
            int m = i / BK, kk = i % BK;
            int gm = block_m + m, gk = k0 + kk;
            As[kk][m] = (gm < M && gk < K) ? A[(size_t)gm * lda + gk] : 0.f;
        }
        for (int i = tid; i < BN * BK; i += THREADS) {
            int n = i / BK, kk = i % BK;
            int gn = block_n + n, gk = k0 + kk;
            Bs[kk][n] = (gn < N && gk < K) ? B[(size_t)gn * ldb + gk] : 0.f;
        }
        __syncthreads();
#pragma unroll
        for (int kk = 0; kk < BK; kk++) {
            float a[TM], b[TN];
#pragma unroll
            for (int i = 0; i < TM; i++) a[i] = As[kk][ty * TM + i];
#pragma unroll
            for (int j = 0; j < TN; j++) b[j] = Bs[kk][tx * TN + j];
#pragma unroll
            for (int i = 0; i < TM; i++)
#pragma unroll
                for (int j = 0; j < TN; j++) acc[i][j] += a[i] * b[j];
        }
        __syncthreads();
    }
#pragma unroll
    for (int i = 0; i < TM; i++) {
        int gm = block_m + ty * TM + i;
        if (gm >= M) continue;
#pragma unroll
        for (int j = 0; j < TN; j++) {
            int gn = block_n + tx * TN + j;
            if (gn >= N) continue;
            float v = acc[i][j];
            if (bias1) v += bias1[gn];
            if (bias2) v += bias2[gn];
            if (RELU) v = fmaxf(v, 0.f);
            C[(size_t)gm * ldc + gn] = v;
        }
    }
}

// ---------------------------------------------------------------------------
// Persistent fused LSTM: 512 blocks (2/CU), one launch for all 26 steps.
// Block owns hh0=bid*2 (2 hidden slots) x 4 gate types = 8 W_hh rows in LDS.
// hT[k][b] (1024x64 fp32) ping-pong in global; c-state in registers.
// Grid barrier: device-scope atomics (acq/rel, agent scope) for cross-XCD.
// ---------------------------------------------------------------------------
__device__ __forceinline__ void grid_barrier(unsigned* bar, unsigned target) {
    __syncthreads();
    if (threadIdx.x == 0) {
        __hip_atomic_fetch_add(bar, 1u, __ATOMIC_ACQ_REL, __HIP_MEMORY_SCOPE_AGENT);
        while (__hip_atomic_load(bar, __ATOMIC_ACQUIRE, __HIP_MEMORY_SCOPE_AGENT) < target) {
            __builtin_amdgcn_s_sleep(1);
        }
    }
    __syncthreads();
}

__global__ void __launch_bounds__(256, 2)
lstm_persist(const float* __restrict__ xw, const float* __restrict__ W_hh,
             float* __restrict__ hs, float* __restrict__ hTa, float* __restrict__ hTb,
             unsigned* __restrict__ bar) {
    __shared__ float Wl[8 * 1028];     // 8 rows x 1024 (+4 pad vs bank conflicts)
    __shared__ float part[4 * 32 * 2 * 8];  // [w][bb][gg][j*2+q]
    const int tid = threadIdx.x;
    const int hh0 = blockIdx.x * 2;

    // stage W_hh rows {j*1024 + hh0 + gg : j<4, gg<2} once
    for (int u = tid; u < 8 * 1024; u += 256) {
        int r = u >> 10, k = u & 1023;
        int grow = (r >> 1) * 1024 + hh0 + (r & 1);
        Wl[r * 1028 + k] = W_hh[(size_t)grow * 1024 + k];
    }
    const int w = tid >> 6;
    const int lane = tid & 63;
    const int gg = lane & 1;
    const int bb = lane >> 1;          // 0..31, batches 2bb,2bb+1
    const int pb = tid & 63;           // pointwise batch
    const int phl = (tid >> 6) & 1;    // pointwise hh_loc (threads 0..127 active)
    float creg = 0.f;
    __syncthreads();

    for (int step = 0; step < TT; step++) {
        const float* hTc = (step & 1) ? hTb : hTa;
        float* hTn = (step & 1) ? hTa : hTb;
        if (step > 0) {
            float acc[4][2];
#pragma unroll
            for (int j = 0; j < 4; j++) { acc[j][0] = 0.f; acc[j][1] = 0.f; }
            const int k0 = w * 256;
#pragma unroll 2
            for (int kk = 0; kk < 256; kk += 4) {
                int k = k0 + kk;
                float2 h0 = *(const float2*)&hTc[(k + 0) * 64 + 2 * bb];
                float2 h1 = *(const float2*)&hTc[(k + 1) * 64 + 2 * bb];
                float2 h2 = *(const float2*)&hTc[(k + 2) * 64 + 2 * bb];
                float2 h3 = *(const float2*)&hTc[(k + 3) * 64 + 2 * bb];
#pragma unroll
                for (int j = 0; j < 4; j++) {
                    float4 wv = *(const float4*)&Wl[(2 * j + gg) * 1028 + k];
                    acc[j][0] = fmaf(wv.x, h0.x, acc[j][0]);
                    acc[j][0] = fmaf(wv.y, h1.x, acc[j][0]);
                    acc[j][0] = fmaf(wv.z, h2.x, acc[j][0]);
                    acc[j][0] = fmaf(wv.w, h3.x, acc[j][0]);
                    acc[j][1] = fmaf(wv.x, h0.y, acc[j][1]);
                    acc[j][1] = fmaf(wv.y, h1.y, acc[j][1]);
                    acc[j][1] = fmaf(wv.z, h2.y, acc[j][1]);
                    acc[j][1] = fmaf(wv.w, h3.y, acc[j][1]);
                }
            }
#pragma unroll
            for (int j = 0; j < 4; j++) {
#pragma unroll
                for (int q = 0; q < 2; q++)
                    part[((w * 32 + bb) * 2 + gg) * 8 + j * 2 + q] = acc[j][q];
            }
            __syncthreads();
        }
        // pointwise: threads 0..127 handle (hh0+phl, pb)
        if (tid < 128) {
            int hh = hh0 + phl;
            float g4[4];
#pragma unroll
            for (int j = 0; j < 4; j++) {
                float sum = xw[((size_t)pb * TT + step) * 4096 + j * 1024 + hh];
                if (step > 0) {
#pragma unroll
                    for (int ww = 0; ww < 4; ww++)
                        sum += part[((ww * 32 + (pb >> 1)) * 2 + phl) * 8 + j * 2 + (pb & 1)];
                }
                g4[j] = sum;
            }
            float si = 1.f / (1.f + expf(-g4[0]));
            float sf = 1.f / (1.f + expf(-g4[1]));
            float tg = tanhf(g4[2]);
            float so = 1.f / (1.f + expf(-g4[3]));
            creg = sf * creg + si * tg;
            float hn = so * tanhf(creg);
            hTn[hh * 64 + pb] = hn;
            hs[(size_t)step * BB * HH + (size_t)pb * HH + hh] = hn;
        }
        if (step < TT - 1) grid_barrier(bar, 512u * (unsigned)(step + 1));
    }
}

__global__ void qa2_kernel(const float* __restrict__ qa, const float* __restrict__ Wq2,
                           const float* __restrict__ bq2, float* __restrict__ out) {
    int tid = blockIdx.x * blockDim.x + threadIdx.x;
    if (tid >= BB * 2 * TT) return;
    int t = tid % TT;
    int bg = tid / TT;
    int g = bg & 1;
    const float* arow = qa + ((size_t)t * BB + (bg >> 1)) * 512;
    const float* wrow = Wq2 + g * 512;
    float acc = bq2[g];
    for (int o = 0; o < 512; o++) acc += wrow[o] * arow[o];
    out[tid] = acc;
}

__global__ void ia2_kernel(const float* __restrict__ ia, const float* __restrict__ Wi2,
                           const float* __restrict__ bi2, float* __restrict__ out) {
    int tid = blockIdx.x * blockDim.x + threadIdx.x;
    if (tid >= BB * 2 * SS) return;
    int s = tid % SS;
    int bg = tid / SS;
    int g = bg & 1;
    int b = bg >> 1;
    const float* arow = ia + ((size_t)b * SS + s) * 512;
    const float* wrow = Wi2 + g * 512;
    float acc = bi2[g];
    for (int o = 0; o < 512; o++) acc += wrow[o] * arow[o];
    out[tid] = acc;
}

__global__ void softmax_small(float* __restrict__ x, int rows, int len) {
    int r = blockIdx.x * blockDim.x + threadIdx.x;
    if (r >= rows) return;
    float* xr = x + (size_t)r * len;
    float mx = -1e30f;
    for (int i = 0; i < len; i++) mx = fmaxf(mx, xr[i]);
    float s = 0.f;
    for (int i = 0; i < len; i++) s += expf(xr[i] - mx);
    float inv = 1.f / s;
    for (int i = 0; i < len; i++) xr[i] = expf(xr[i] - mx) * inv;
}

__global__ void qfeat_kernel(const float* __restrict__ qatt, const float* __restrict__ hs,
                             float* __restrict__ qf) {
    int idx = blockIdx.x * blockDim.x + threadIdx.x;
    if (idx >= BB * 2048) return;
    int b = idx >> 11;
    int gh = idx & 2047;
    int g = gh >> 10;
    int hh = gh & 1023;
    float acc = 0.f;
    for (int t = 0; t < TT; t++)
        acc += qatt[((size_t)b * 2 + g) * TT + t] * hs[((size_t)t * BB + b) * HH + hh];
    qf[idx] = acc;
}

// ---------------------------------------------------------------------------
// MCB1 stage A: LDS-privatized scatter + FACTOR fold -> afold[b][t] fp32
// ---------------------------------------------------------------------------
__global__ void sketch_fold(const float* __restrict__ img_feat, const int* __restrict__ h1x,
                            const int* __restrict__ s1x, float* __restrict__ afold) {
    __shared__ float sl[FOLD_R + 196];
    const int b = blockIdx.y;
    const int r0 = blockIdx.x * FOLD_R;
    for (int i = threadIdx.x; i < FOLD_R + 196; i += 256) sl[i] = 0.f;
    __syncthreads();
    for (int i = threadIdx.x; i < NITEMS; i += 256) {
        int h = h1x[i];
        int d = h - r0;
        if (d < 0) d += D1;
        if (d < FOLD_R + 196) {
            int f = i / SS, s = i - f * SS;
            float val = img_feat[((size_t)b * SS + s) * FEAT + f]
                        * (float)(2 * s1x[i] - 1);
            atomicAdd(&sl[d], val);
        }
    }
    __syncthreads();
    float* ab = afold + (size_t)b * D1;
    for (int t = threadIdx.x; t < FOLD_R; t += 256) {
        int g = r0 + t;
        if (g >= D1) break;
        ab[g] = sl[t] + sl[t + 49] + sl[t + 98] + sl[t + 147] + sl[t + 196];
    }
}

__device__ __forceinline__ unsigned short bf16_rne(float x) {
    unsigned u = __float_as_uint(x);
    u += 0x7fffu + ((u >> 16) & 1u);
    return (unsigned short)(u >> 16);
}

// ---------------------------------------------------------------------------
// MCB1 stage B: transpose afold[b][t] -> atT[t][32 x bf16x2], with wrap pad.
// ---------------------------------------------------------------------------
__global__ void transpose_bf16(const float* __restrict__ afold, unsigned* __restrict__ atT) {
    __shared__ float L[64][65];
    const int t0 = blockIdx.x * 64;
    const int tid = threadIdx.x;
    for (int c = 0; c < 16; c++) {
        int idx = c * 256 + tid;          // b*64 + i
        int b = idx >> 6, i = idx & 63;
        int t = t0 + i;
        int src_t = (t < D1) ? t : t - D1;
        L[i][b] = afold[(size_t)b * D1 + src_t];
    }
    __syncthreads();
    for (int c = 0; c < 8; c++) {
        int u = c * 256 + tid;            // t_loc*32 + qq
        int t_loc = u >> 5, qq = u & 31;
        int t = t0 + t_loc;
        if (t >= NROWS) continue;
        unsigned lo = bf16_rne(L[t_loc][2 * qq]);
        unsigned hi = bf16_rne(L[t_loc][2 * qq + 1]);
        atT[(size_t)t * 32 + qq] = lo | (hi << 16);
    }
}

// ---------------------------------------------------------------------------
// Bitonic sort of (h1q, index), 2048 elements, one block of 1024 threads.
// ---------------------------------------------------------------------------
__global__ void sort_pv(const int* __restrict__ h1q, int* __restrict__ pS,
                        int* __restrict__ permS) {
    __shared__ int k[2048], v[2048];
    const int t = threadIdx.x;
    k[t] = h1q[t];          v[t] = t;
    k[t + 1024] = h1q[t + 1024]; v[t + 1024] = t + 1024;
    for (int size = 2; size <= 2048; size <<= 1) {
        for (int stride = size >> 1; stride > 0; stride >>= 1) {
            __syncthreads();
            int pos = 2 * t - (t & (stride - 1));
            bool asc = ((pos & size) == 0);
            int a = k[pos], b = k[pos + stride];
            if ((a > b) == asc) {
                k[pos] = b; k[pos + stride] = a;
                int tmp = v[pos]; v[pos] = v[pos + stride]; v[pos + stride] = tmp;
            }
        }
    }
    __syncthreads();
    pS[t] = k[t]; pS[t + 1024] = k[t + 1024];
    permS[t] = v[t]; permS[t + 1024] = v[t + 1024];
}

// vTs[r][q] = pack_bf16( qf[2q][j]*sgn[j], qf[2q+1][j]*sgn[j] ), j = permS[r]
__global__ void vts_build(const float* __restrict__ qf, const int* __restrict__ s1q,
                          const int* __restrict__ permS, unsigned* __restrict__ vTs) {
    int gid = blockIdx.x * blockDim.x + threadIdx.x;
    if (gid >= 2048 * 32) return;
    int r = gid >> 5, q = gid & 31;
    int j = permS[r];
    float sg = (float)(2 * s1q[j] - 1);
    unsigned lo = bf16_rne(qf[(size_t)(2 * q) * 2048 + j] * sg);
    unsigned hi = bf16_rne(qf[(size_t)(2 * q + 1) * 2048 + j] * sg);
    vTs[gid] = lo | (hi << 16);
}

__device__ __forceinline__ int lbound(const int* a, int x) {
    int lo = 0, hi = 2048;
    while (lo < hi) { int mid = (lo + hi) >> 1; if (a[mid] < x) lo = mid + 1; else hi = mid; }
    return lo;
}

// ---------------------------------------------------------------------------
// MCB1 gather, batch-major bf16, phase-partitioned for L2 residency.
// ---------------------------------------------------------------------------
__global__ void __launch_bounds__(256, 8)
mcb1_gather3(const unsigned* __restrict__ atT, const unsigned* __restrict__ vTs,
             const int* __restrict__ pS, float* __restrict__ iq) {
    __shared__ int sp[2048];
    for (int i = threadIdx.x; i < 2048; i += 256) sp[i] = pS[i];
    __syncthreads();

    const int s = blockIdx.y;
    const int w = threadIdx.x >> 5;
    const int q = threadIdx.x & 31;
    const int m0 = blockIdx.x * 64 + w * 8;
    const int m0c = (m0 <= 992) ? m0 : 992;
    const int tb0 = 245 * m0c + s;

    const unsigned* __restrict__ atq = atT + q;
    const unsigned* __restrict__ vtq = vTs + q;

    float accL[8], accH[8];
#pragma unroll
    for (int kk = 0; kk < 8; kk++) { accL[kk] = 0.f; accH[kk] = 0.f; }

    for (int c = 0; c < NP; c++) {
        const int A0 = c * WP;
        const int A1 = A0 + WP;
        int PL = tb0 - A1 + 1; if (PL < 0) PL += D1; if (PL >= D1) PL -= D1;
        int PH = tb0 - A0;     if (PH < 0) PH += D1; if (PH >= D1) PH -= D1;
        int r0a, r1a, r0b, r1b;
        if (PL <= PH) {
            r0a = lbound(sp, PL); r1a = lbound(sp, PH + 1);
            r0b = 0; r1b = 0;
        } else {
            r0a = lbound(sp, PL); r1a = 2048;
            r0b = 0; r1b = lbound(sp, PH + 1);
        }
#pragma unroll 1
        for (int seg = 0; seg < 2; seg++) {
            int rs = seg ? r0b : r0a;
            int re = seg ? r1b : r1a;
            for (int r = rs; r < re; r++) {
                int p = sp[r];
                int qe = (p <= tb0) ? -p : D1 - p;
                unsigned vv = vtq[r * 32];
                float vlo = __uint_as_float(vv << 16);
                float vhi = __uint_as_float(vv & 0xffff0000u);
                const unsigned* row = atq + (size_t)(tb0 + qe) * 32;
#pragma unroll
                for (int kk = 0; kk < 8; kk++) {
                    unsigned u = row[kk * 245 * 32];
                    float alo = __uint_as_float(u << 16);
                    float ahi = __uint_as_float(u & 0xffff0000u);
                    accL[kk] = fmaf(vlo, alo, accL[kk]);
                    accH[kk] = fmaf(vhi, ahi, accH[kk]);
                }
            }
        }
    }

    if (m0 <= 992) {
        float* o0 = iq + ((size_t)(2 * q) * SS + s) * MOUT + m0;
        float* o1 = iq + ((size_t)(2 * q + 1) * SS + s) * MOUT + m0;
#pragma unroll
        for (int kk = 0; kk < 8; kk++) { o0[kk] = accL[kk]; o1[kk] = accH[kk]; }
    }
}

__global__ void ssqrt_l2norm(float* __restrict__ x, int n) {
    __shared__ float red[256];
    __shared__ float inv_s;
    int b = blockIdx.x;
    float* xb = x + (size_t)b * n;
    float ss = 0.f;
    for (int i = threadIdx.x; i < n; i += 256) {
        float v = xb[i];
        float y = (v >= 0.f) ? sqrtf(v) : -sqrtf(-v);
        xb[i] = y;
        ss += y * y;
    }
    red[threadIdx.x] = ss;
    __syncthreads();
    for (int s = 128; s > 0; s >>= 1) {
        if (threadIdx.x < s) red[threadIdx.x] += red[threadIdx.x + s];
        __syncthreads();
    }
    if (threadIdx.x == 0) inv_s = 1.f / fmaxf(sqrtf(red[0]), 1e-12f);
    __syncthreads();
    float inv = inv_s;
    for (int i = threadIdx.x; i < n; i += 256) xb[i] *= inv;
}

__global__ void ifeat_kernel(const float* __restrict__ iatt, const float* __restrict__ img_feat,
                             float* __restrict__ ifeat) {
    int idx = blockIdx.x * blockDim.x + threadIdx.x;
    if (idx >= BB * 4096) return;
    int b = idx >> 12;
    int gf = idx & 4095;
    int g = gf >> 11;
    int f = gf & 2047;
    float acc = 0.f;
    for (int s = 0; s < SS; s++)
        acc += iatt[((size_t)b * 2 + g) * SS + s] * img_feat[((size_t)b * SS + s) * FEAT + f];
    ifeat[idx] = acc;
}

__global__ void mcb2_scatter(const float* __restrict__ ifeat, const int* __restrict__ h2i,
                             const int* __restrict__ s2i, float* __restrict__ atil2) {
    int tid = blockIdx.x * blockDim.x + threadIdx.x;
    if (tid >= BB * 4096) return;
    int i = tid & 4095;
    int b = tid >> 12;
    float v = ifeat[tid] * (float)(2 * s2i[i] - 1);
    int p = h2i[i];
    float* ab = atil2 + (size_t)b * D2;
#pragma unroll
    for (int f = 0; f < 5; f++) {
        int t = p - f;
        if (t < 0) t += D2;
        atomicAdd(&ab[t], v);
    }
}

__global__ void mcb2_gather(const float* __restrict__ atil2, const float* __restrict__ qf,
                            const int* __restrict__ h2q, const int* __restrict__ s2q,
                            float* __restrict__ z) {
    __shared__ float sa[D2];
    __shared__ int sp[2048];
    __shared__ float sv[2048];
    int b = blockIdx.y;
    for (int i = threadIdx.x; i < D2; i += 256) sa[i] = atil2[(size_t)b * D2 + i];
    const float* qb = qf + (size_t)b * 2048;
    for (int j = threadIdx.x; j < 2048; j += 256) {
        sp[j] = h2q[j];
        sv[j] = qb[j] * (float)(2 * s2q[j] - 1);
    }
    __syncthreads();
    int m = blockIdx.x * 256 + threadIdx.x;
    if (m >= MOUT) return;
    int base = 5 * m + D2;
    float acc = 0.f;
#pragma unroll 4
    for (int j = 0; j < 2048; j++) {
        int addr = base - sp[j];
        if (addr >= D2) addr -= D2;
        acc += sv[j] * sa[addr];
    }
    z[(size_t)b * MOUT + m] = acc;
}

__global__ void softmax_rows(const float* __restrict__ logits, float* __restrict__ out, int n) {
    __shared__ float red[256];
    int b = blockIdx.x;
    const float* xr = logits + (size_t)b * n;
    float* orow = out + (size_t)b * n;
    float mx = -1e30f;
    for (int i = threadIdx.x; i < n; i += 256) mx = fmaxf(mx, xr[i]);
    red[threadIdx.x] = mx;
    __syncthreads();
    for (int s = 128; s > 0; s >>= 1) {
        if (threadIdx.x < s) red[threadIdx.x] = fmaxf(red[threadIdx.x], red[threadIdx.x + s]);
        __syncthreads();
    }
    mx = red[0];
    __syncthreads();
    float sum = 0.f;
    for (int i = threadIdx.x; i < n; i += 256) sum += expf(xr[i] - mx);
    red[threadIdx.x] = sum;
    __syncthreads();
    for (int s = 128; s > 0; s >>= 1) {
        if (threadIdx.x < s) red[threadIdx.x] += red[threadIdx.x + s];
        __syncthreads();
    }
    float inv = 1.f / red[0];
    for (int i = threadIdx.x; i < n; i += 256) orow[i] = expf(xr[i] - mx) * inv;
}

extern "C" void kernel_launch(void* const* d_in, const int* in_sizes, int n_in,
                              void* d_out, int out_size, void* d_ws, size_t ws_size,
                              hipStream_t stream) {
    (void)in_sizes; (void)n_in; (void)out_size; (void)ws_size;
    const float* ques = (const float*)d_in[0];
    const float* img  = (const float*)d_in[1];
    const float* W_ih = (const float*)d_in[2];
    const float* W_hh = (const float*)d_in[3];
    const float* b_ih = (const float*)d_in[4];
    const float* b_hh = (const float*)d_in[5];
    const float* Wq1  = (const float*)d_in[6];
    const float* bq1  = (const float*)d_in[7];
    const float* Wq2  = (const float*)d_in[8];
    const float* bq2  = (const float*)d_in[9];
    const float* Wi1  = (const float*)d_in[10];
    const float* bi1  = (const float*)d_in[11];
    const float* Wi2  = (const float*)d_in[12];
    const float* bi2  = (const float*)d_in[13];
    const float* Wp   = (const float*)d_in[14];
    const float* bp   = (const float*)d_in[15];
    const int* h1x = (const int*)d_in[16];
    const int* s1x = (const int*)d_in[17];
    const int* h1q = (const int*)d_in[18];
    const int* s1q = (const int*)d_in[19];
    const int* h2i = (const int*)d_in[20];
    const int* s2i = (const int*)d_in[21];
    const int* h2q = (const int*)d_in[22];
    const int* s2q = (const int*)d_in[23];
    float* out = (float*)d_out;

    // Workspace layout (4 B units), same two-phase overlap as R3.
    float* ws = (float*)d_ws;
    float* xw    = ws;                 // 6,815,744
    float* hs    = ws + 6815744;       // 1,703,936
    float* hTa   = ws + 8519680;       // 65,536
    float* hTb   = ws + 8585216;       // 65,536
    unsigned* bar = (unsigned*)(ws + 8650752);  // 1 (region 262,144 free)
    float* qa    = ws + 8912896;       // 851,968
    float* qatt  = ws + 9764864;       // 4,096
    float* afold = ws;                 // 15,680,000 (overwrites phase1)
    // phase2 smalls (inside region A, alive after transpose)
    float* iq     = ws;                // 3,136,000
    float* ia     = ws + 3136000;      // 1,605,632
    float* iatt   = ws + 4741632;      // 8,192
    float* ifeat  = ws + 4749824;      // 262,144
    float* atil2  = ws + 5011968;      // 320,000
    float* z      = ws + 5331968;      // 64,000
    float* logits = ws + 5395968;      // 192,000
    // Region B/C
    unsigned* atT  = (unsigned*)(ws + 15680000);  // NROWS*32 = 7,905,536
    float* qf      = ws + 15680000 + 7905536;     // 131,072
    unsigned* vTs  = (unsigned*)(qf + 131072);    // 65,536
    int* pS        = (int*)(vTs + 65536);         // 2,048
    int* permS     = pS + 2048;                   // 2,048

    // ---- sort (independent) ----
    sort_pv<<<1, 1024, 0, stream>>>(h1q, pS, permS);

    // ---- LSTM ----
    hipMemsetAsync(bar, 0, 4, stream);
    {   // xW[(b*T+t), g] = ques(b,t,:) . W_ih(g,:) + b_ih + b_hh
        dim3 grid(4096 / 64, (BB * TT + 127) / 128);
        gemm_abt<128, 64, 16, 8, 4, false><<<grid, 256, 0, stream>>>(
            ques, W_ih, b_ih, b_hh, xw, BB * TT, 4 * HH, EE, EE, EE, 4 * HH);
    }
    lstm_persist<<<512, 256, 0, stream>>>(xw, W_hh, hs, hTa, hTb, bar);
    // ---- question attention ----
    {
        dim3 grid(512 / 64, (TT * BB + 127) / 128);
        gemm_abt<128, 64, 16, 8, 4, true><<<grid, 256, 0, stream>>>(
            hs, Wq1, bq1, nullptr, qa, TT * BB, 512, HH, HH, HH, 512);
    }
    qa2_kernel<<<(BB * 2 * TT + 255) / 256, 256, 0, stream>>>(qa, Wq2, bq2, qatt);
    softmax_small<<<1, 128, 0, stream>>>(qatt, BB * 2, TT);
    qfeat_kernel<<<(BB * 2048) / 256, 256, 0, stream>>>(qatt, hs, qf);
    // ---- MCB1: fold -> transpose(bf16) -> phased gather ----
    {
        dim3 grid(FOLD_NR, BB);
        sketch_fold<<<grid, 256, 0, stream>>>(img, h1x, s1x, afold);
    }
    {
        int nblk = (NROWS + 63) / 64;
        transpose_bf16<<<nblk, 256, 0, stream>>>(afold, atT);
    }
    vts_build<<<(2048 * 32) / 256, 256, 0, stream>>>(qf, s1q, permS, vTs);
    {
        dim3 grid(16, SS);
        mcb1_gather3<<<grid, 256, 0, stream>>>(atT, vTs, pS, iq);
    }
    ssqrt_l2norm<<<BB, 256, 0, stream>>>(iq, MOUT * SS);
    {
        dim3 grid(512 / 64, (BB * SS + 127) / 128);
        gemm_abt<128, 64, 16, 8, 4, true><<<grid, 256, 0, stream>>>(
            iq, Wi1, bi1, nullptr, ia, BB * SS, 512, MOUT, MOUT, MOUT, 512);
    }
    ia2_kernel<<<(BB * 2 * SS + 255) / 256, 256, 0, stream>>>(ia, Wi2, bi2, iatt);
    softmax_small<<<1, 128, 0, stream>>>(iatt, BB * 2, SS);
    ifeat_kernel<<<(BB * 4096) / 256, 256, 0, stream>>>(iatt, img, ifeat);
    // ---- MCB2 + classifier ----
    hipMemsetAsync(atil2, 0, (size_t)BB * D2 * 4, stream);
    mcb2_scatter<<<(BB * 4096) / 256, 256, 0, stream>>>(ifeat, h2i, s2i, atil2);
    {
        dim3 grid(4, BB);
        mcb2_gather<<<grid, 256, 0, stream>>>(atil2, qf, h2q, s2q, z);
    }
    ssqrt_l2norm<<<BB, 256, 0, stream>>>(z, MOUT);
    {
        dim3 grid((VOCAB + 63) / 64, 4);
        gemm_abt<16, 64, 16, 2, 2, false><<<grid, 256, 0, stream>>>(
            z, Wp, bp, nullptr, logits, BB, VOCAB, MOUT, MOUT, MOUT, VOCAB);
    }
    softmax_rows<<<BB, 256, 0, stream>>>(logits, out, VOCAB);
}